// Round 4
// baseline (307.684 us; speedup 1.0000x reference)
//
#include <hip/hip_runtime.h>
#include <hip/hip_bf16.h>
#include <stdint.h>

// TT linear 4096->4096, B=2048, ranks (1,16,16,16,1), modes 8^4.
// R4: zero-LDS zero-barrier register GEMM (AITER-flatmm style):
// 128-thr blocks, 2 indep waves x (64x128 tile), BK=32, frags loaded
// straight global->VGPR with 1-tile ping-pong prefetch. W build + x cvt
// fused into one kernel.

typedef __bf16 bf16_t;
typedef __bf16 bf16x8 __attribute__((ext_vector_type(8)));
typedef float floatx4 __attribute__((ext_vector_type(4)));

#define BATCH_N 2048
#define KD 4096
#define ND 4096

// ---- fused: blocks [0,4096) build W; blocks [4096,8192) cvt x->bf16 ----
__global__ __launch_bounds__(256) void prep(const float* __restrict__ x,
                                            const float* __restrict__ c0,
                                            const float* __restrict__ c1,
                                            const float* __restrict__ c2,
                                            const float* __restrict__ c3,
                                            bf16_t* __restrict__ W,
                                            bf16_t* __restrict__ xb) {
    __shared__ float c0s[8 * 16];       // [m0][r1]
    __shared__ float c1s[16 * 8 * 16];  // [r1][m1][r2]
    __shared__ float c2s[16 * 8 * 16];  // [r2][n2][r3]
    __shared__ float c3s[16 * 8];       // [r3][n3]
    __shared__ float Ps[64 * 16];       // [m01][r2]
    __shared__ float T1s[16 * 64];      // [r2][n23]
    const int t = threadIdx.x;

    if (blockIdx.x >= 4096) {           // ---- cvt_x part ----
        int g = (blockIdx.x - 4096) * 256 + t;
        const float4* xv = (const float4*)x;
        float4 a = xv[g * 2];
        float4 b = xv[g * 2 + 1];
        bf16x8 o;
        o[0] = (bf16_t)a.x; o[1] = (bf16_t)a.y; o[2] = (bf16_t)a.z; o[3] = (bf16_t)a.w;
        o[4] = (bf16_t)b.x; o[5] = (bf16_t)b.y; o[6] = (bf16_t)b.z; o[7] = (bf16_t)b.w;
        ((bf16x8*)xb)[g] = o;
        return;
    }

    // ---- build_w part: one block per (M23, N01) 64x64 W-tile ----
    const int b = blockIdx.x;
    const int M23 = b >> 6, N01 = b & 63;
    const int n0 = N01 >> 3, n1 = N01 & 7, m2 = M23 >> 3, m3 = M23 & 7;

    if (t < 128) c0s[t] = c0[(t >> 4) * 128 + n0 * 16 + (t & 15)];
    if (t < 128) c3s[t] = c3[((t >> 3) * 8 + m3) * 8 + (t & 7)];
    for (int i = t; i < 2048; i += 256) {
        int r1 = i >> 7, m1 = (i >> 4) & 7, r2 = i & 15;
        c1s[i] = c1[(r1 * 8 + m1) * 128 + n1 * 16 + r2];
    }
    for (int i = t; i < 2048; i += 256) {
        int r2 = i >> 7, n2 = (i >> 4) & 7, r3 = i & 15;
        c2s[i] = c2[(r2 * 8 + m2) * 128 + n2 * 16 + r3];
    }
    __syncthreads();

    for (int i = t; i < 1024; i += 256) {   // Ps[m01][r2]
        int m01 = i >> 4, r2 = i & 15, m0 = m01 >> 3, m1 = m01 & 7;
        float s = 0.f;
#pragma unroll
        for (int r1 = 0; r1 < 16; ++r1)
            s += c0s[m0 * 16 + r1] * c1s[r1 * 128 + m1 * 16 + r2];
        Ps[i] = s;
    }
    for (int i = t; i < 1024; i += 256) {   // T1s[r2][n23]
        int r2 = i >> 6, n23 = i & 63, n2 = n23 >> 3, n3 = n23 & 7;
        float s = 0.f;
#pragma unroll
        for (int r3 = 0; r3 < 16; ++r3)
            s += c2s[r2 * 128 + n2 * 16 + r3] * c3s[r3 * 8 + n3];
        T1s[i] = s;
    }
    __syncthreads();

    const int n23 = t & 63, q = t >> 6;
#pragma unroll
    for (int g = 0; g < 16; ++g) {
        int m01 = q * 16 + g;
        float s = 0.f;
#pragma unroll
        for (int r2 = 0; r2 < 16; ++r2) s += Ps[m01 * 16 + r2] * T1s[r2 * 64 + n23];
        W[(size_t)(m01 * 64 + M23) * 4096 + N01 * 64 + n23] = (bf16_t)s;
    }
}

// ---- BT GEMM, register-resident: C[m,n] = sum_k A[m,k]*B[n,k] + bias[n]
// grid (32 n, 16 m), 128 threads = 2 independent waves (wave w: rows
// bm*128 + w*64 .. +64, all 128 cols of the n-tile). No LDS, no barriers:
// A/B fragments loaded global->VGPR (16x16x32 layout: lane holds
// row lane&15, k-chunk (lane>>4)*8 -> 16 full 64B lines per load instr).
// Hand ping-pong one 32-wide K-tile ahead so the compiler pipelines with
// partial vmcnt waits; same-block waves share B lines through L1.
__global__ __launch_bounds__(128, 2) void gemm_reg(const bf16_t* __restrict__ A,
                                                   const bf16_t* __restrict__ B,
                                                   const float* __restrict__ bias,
                                                   float* __restrict__ C) {
    const int t = threadIdx.x;
    const int lane = t & 63, wave = t >> 6;
    const int bn = blockIdx.x, bm = blockIdx.y;   // 32 x 16
    const int fr = lane & 15;
    const int fk = (lane >> 4) * 8;

    const bf16_t* Ap = A + (size_t)(bm * 128 + wave * 64 + fr) * KD + fk;
    const bf16_t* Bp = B + (size_t)(bn * 128 + fr) * KD + fk;

    floatx4 acc[4][8];
    floatx4 zero = {0.f, 0.f, 0.f, 0.f};
#pragma unroll
    for (int i = 0; i < 4; ++i)
#pragma unroll
        for (int j = 0; j < 8; ++j) acc[i][j] = zero;

    bf16x8 a0[4], b0[8], a1[4], b1[8];

#define LDA(f, k)                                                         \
    {                                                                     \
        _Pragma("unroll") for (int im = 0; im < 4; ++im)                  \
            f[im] = *(const bf16x8*)(Ap + (size_t)(im * 16) * KD + (k));  \
    }
#define LDB(f, k)                                                         \
    {                                                                     \
        _Pragma("unroll") for (int in = 0; in < 8; ++in)                  \
            f[in] = *(const bf16x8*)(Bp + (size_t)(in * 16) * KD + (k));  \
    }
#define MM(fa, fb)                                                        \
    {                                                                     \
        _Pragma("unroll") for (int im = 0; im < 4; ++im)                  \
            _Pragma("unroll") for (int in = 0; in < 8; ++in)              \
                acc[im][in] = __builtin_amdgcn_mfma_f32_16x16x32_bf16(    \
                    fa[im], fb[in], acc[im][in], 0, 0, 0);                \
    }

    LDA(a0, 0); LDB(b0, 0);
    for (int kb = 0; kb < KD - 64; kb += 64) {
        LDA(a1, kb + 32); LDB(b1, kb + 32);
        MM(a0, b0);
        LDA(a0, kb + 64); LDB(b0, kb + 64);
        MM(a1, b1);
    }
    LDA(a1, KD - 32); LDB(b1, KD - 32);
    MM(a0, b0);
    MM(a1, b1);

    // epilogue: D[m = (lane>>4)*4 + r][n = lane&15] per 16x16 frag
    const int rl = lane >> 4, cl = lane & 15;
    const size_t rbase = (size_t)bm * 128 + wave * 64;
    const int cbase = bn * 128;
#pragma unroll
    for (int im = 0; im < 4; ++im) {
#pragma unroll
        for (int in = 0; in < 8; ++in) {
            int col = cbase + in * 16 + cl;
            float bv = bias[col];
#pragma unroll
            for (int r = 0; r < 4; ++r) {
                size_t row = rbase + im * 16 + rl * 4 + r;
                C[row * ND + col] = acc[im][in][r] + bv;
            }
        }
    }
#undef LDA
#undef LDB
#undef MM
}

extern "C" void kernel_launch(void* const* d_in, const int* in_sizes, int n_in,
                              void* d_out, int out_size, void* d_ws, size_t ws_size,
                              hipStream_t stream) {
    const float* x  = (const float*)d_in[0];
    const float* c0 = (const float*)d_in[1];
    const float* c1 = (const float*)d_in[2];
    const float* c2 = (const float*)d_in[3];
    const float* c3 = (const float*)d_in[4];
    const float* bias = (const float*)d_in[5];
    float* out = (float*)d_out;

    char* ws = (char*)d_ws;
    bf16_t* Xb = (bf16_t*)ws;                 // 16 MiB
    bf16_t* W  = (bf16_t*)(ws + (16u << 20)); // 32 MiB

    prep<<<8192, 256, 0, stream>>>(x, c0, c1, c2, c3, W, Xb);
    dim3 grid(ND / 128, BATCH_N / 128);
    gemm_reg<<<grid, 128, 0, stream>>>(Xb, W, bias, out);
}

// Round 5
// 212.323 us; speedup vs baseline: 1.4491x; 1.4491x over previous
//
#include <hip/hip_runtime.h>
#include <hip/hip_bf16.h>
#include <stdint.h>

// TT linear 4096->4096, B=2048, ranks (1,16,16,16,1), modes 8^4.
// R5: both GEMM operands pre-swizzled into MFMA fragment order so the
// K-loop is zero-LDS / zero-barrier with fully-coalesced 1KB register
// loads (AITER-style partial-vmcnt pipeline, depth-2 prefetch).
// Fragment (g, kc): rows g*16..+15, k kc*32..+31; element (row,k) lives at
// frag_base + lane*8 + (k&7), lane = (row&15) | (((k>>3)&3)<<4).

typedef __bf16 bf16_t;
typedef __bf16 bf16x8 __attribute__((ext_vector_type(8)));
typedef float floatx4 __attribute__((ext_vector_type(4)));

#define BATCH_N 2048
#define KD 4096
#define ND 4096

// ---- x fp32 -> bf16 fragment layout -----------------------------------
__global__ __launch_bounds__(256) void cvt_x_frag(const float* __restrict__ x,
                                                  bf16_t* __restrict__ Af) {
    const int t = threadIdx.x;
    const int fid = blockIdx.x * 4 + (t >> 6);    // 16384 frags (128 mg x 128 kc)
    const int lane = t & 63;
    const int mg = fid >> 7, kc = fid & 127;
    const int row = mg * 16 + (lane & 15);
    const int k = kc * 32 + (lane >> 4) * 8;
    const float4* xp = (const float4*)(x + (size_t)row * KD + k);
    float4 a = xp[0], b = xp[1];
    bf16x8 o;
    o[0] = (bf16_t)a.x; o[1] = (bf16_t)a.y; o[2] = (bf16_t)a.z; o[3] = (bf16_t)a.w;
    o[4] = (bf16_t)b.x; o[5] = (bf16_t)b.y; o[6] = (bf16_t)b.z; o[7] = (bf16_t)b.w;
    ((bf16x8*)(Af + (size_t)fid * 512))[lane] = o;
}

// ---- W build, straight into fragment layout ---------------------------
// Block b: M23b = b>>6 (16 consecutive j low-bits), N01 = b&63.
// j = m01*64 + M23b*16 + m23l, i = N01*64 + n23.
__global__ __launch_bounds__(256) void build_w(const float* __restrict__ c0,
                                               const float* __restrict__ c1,
                                               const float* __restrict__ c2,
                                               const float* __restrict__ c3,
                                               bf16_t* __restrict__ Bf) {
    __shared__ float c0s[128];          // [m0*16+r1], n0 fixed
    __shared__ float c1s[2048];         // [r1*128+m1*16+r2], n1 fixed
    __shared__ float c2s[2 * 2048];     // [m2l][r2*128+n2*16+r3]
    __shared__ float c3s[1024];         // [r3*64+m3*8+n3] (== c3 linear)
    __shared__ float Ps[64 * 16];       // [m01*16+r2]
    __shared__ float T1s[16 * 1025];    // [m23l*1025 + r2*64 + n23]
    const int b = blockIdx.x;           // 256
    const int M23b = b >> 6, N01 = b & 63;
    const int n0 = N01 >> 3, n1 = N01 & 7;
    const int t = threadIdx.x;

    if (t < 128) c0s[t] = c0[(t >> 4) * 128 + n0 * 16 + (t & 15)];
    for (int i = t; i < 1024; i += 256) c3s[i] = c3[i];
    for (int i = t; i < 2048; i += 256) {
        int r1 = i >> 7, m1 = (i >> 4) & 7, r2 = i & 15;
        c1s[i] = c1[(r1 * 8 + m1) * 128 + n1 * 16 + r2];
    }
    for (int i = t; i < 4096; i += 256) {
        int m2l = i >> 11, j = i & 2047;
        int r2 = j >> 7, n2 = (j >> 4) & 7, r3 = j & 15;
        c2s[i] = c2[(r2 * 8 + M23b * 2 + m2l) * 128 + n2 * 16 + r3];
    }
    __syncthreads();

    for (int i = t; i < 1024; i += 256) {   // Ps[m01][r2]
        int m01 = i >> 4, r2 = i & 15, m0 = m01 >> 3, m1 = m01 & 7;
        float s = 0.f;
#pragma unroll
        for (int r1 = 0; r1 < 16; ++r1)
            s += c0s[m0 * 16 + r1] * c1s[r1 * 128 + m1 * 16 + r2];
        Ps[i] = s;
    }
    for (int i = t; i < 16384; i += 256) {  // T1s[m23l][r2][n23]
        int m23l = i >> 10, r2 = (i >> 6) & 15, n23 = i & 63;
        int m2l = m23l >> 3, m3 = m23l & 7, n2 = n23 >> 3, n3 = n23 & 7;
        float s = 0.f;
#pragma unroll
        for (int r3 = 0; r3 < 16; ++r3)
            s += c2s[m2l * 2048 + r2 * 128 + n2 * 16 + r3] * c3s[r3 * 64 + m3 * 8 + n3];
        T1s[m23l * 1025 + r2 * 64 + n23] = s;
    }
    __syncthreads();

    // outputs: thread t = (q, lhi, m23l); writes bf16x8 chunks, coalesced/wave
    const int m23l = t & 15, lhi = (t >> 4) & 3, q = t >> 6;
    const int lane = t & 63;
#pragma unroll
    for (int mi = 0; mi < 16; ++mi) {
        int m01 = q * 16 + mi;
#pragma unroll
        for (int n23h = 0; n23h < 2; ++n23h) {
            int n23b = n23h * 32 + lhi * 8;
            bf16x8 o;
#pragma unroll
            for (int n3l = 0; n3l < 8; ++n3l) {
                float s = 0.f;
#pragma unroll
                for (int r2 = 0; r2 < 16; ++r2)
                    s += Ps[m01 * 16 + r2] * T1s[m23l * 1025 + r2 * 64 + n23b + n3l];
                o[n3l] = (bf16_t)s;
            }
            size_t ng = m01 * 4 + M23b, kc = N01 * 2 + n23h;
            ((bf16x8*)(Bf + (ng * 128 + kc) * 512))[lane] = o;
        }
    }
}

// ---- BT GEMM, fragment-direct, zero LDS / zero barriers ---------------
// grid (32 bn, 16 bm) x 256 thr (4 waves 2x2); wave tile 64x64 = 4x4 frags.
// Per K=32 step: 8 coalesced 1KB loads + 16 MFMA; depth-2 prefetch.
__global__ __launch_bounds__(256) void gemm_frag(const bf16_t* __restrict__ Af,
                                                 const bf16_t* __restrict__ Bf,
                                                 const float* __restrict__ bias,
                                                 float* __restrict__ C) {
    const int t = threadIdx.x;
    const int lane = t & 63, wave = t >> 6;
    const int wm = wave >> 1, wn = wave & 1;
    const int bn = blockIdx.x, bm = blockIdx.y;

    const bf16_t* Ap = Af + (size_t)(bm * 8 + wm * 4) * 65536 + (size_t)lane * 8;
    const bf16_t* Bp = Bf + (size_t)(bn * 8 + wn * 4) * 65536 + (size_t)lane * 8;

    floatx4 acc[4][4];
    floatx4 zero = {0.f, 0.f, 0.f, 0.f};
#pragma unroll
    for (int i = 0; i < 4; ++i)
#pragma unroll
        for (int j = 0; j < 4; ++j) acc[i][j] = zero;

    bf16x8 av[2][4], bv[2][4];

#define LD(buf, kc)                                                           \
    {                                                                         \
        _Pragma("unroll") for (int im = 0; im < 4; ++im)                      \
            av[buf][im] = *(const bf16x8*)(Ap + (size_t)im * 65536 + (kc) * 512); \
        _Pragma("unroll") for (int in = 0; in < 4; ++in)                      \
            bv[buf][in] = *(const bf16x8*)(Bp + (size_t)in * 65536 + (kc) * 512); \
    }
#define MM(buf)                                                               \
    {                                                                         \
        _Pragma("unroll") for (int im = 0; im < 4; ++im)                      \
            _Pragma("unroll") for (int in = 0; in < 4; ++in)                  \
                acc[im][in] = __builtin_amdgcn_mfma_f32_16x16x32_bf16(        \
                    av[buf][im], bv[buf][in], acc[im][in], 0, 0, 0);          \
    }

    LD(0, 0);
    LD(1, 1);
    for (int kc = 0; kc < 124; kc += 2) {
        MM(0); LD(0, kc + 2);
        MM(1); LD(1, kc + 3);
    }
    MM(0); LD(0, 126);
    MM(1); LD(1, 127);
    MM(0);
    MM(1);
#undef LD
#undef MM

    // epilogue: D[m=(lane>>4)*4+r][n=lane&15]
    const int rl = lane >> 4, cl = lane & 15;
    const size_t rbase = (size_t)bm * 128 + wm * 64;
    const int cbase = bn * 128 + wn * 64;
#pragma unroll
    for (int im = 0; im < 4; ++im) {
#pragma unroll
        for (int in = 0; in < 4; ++in) {
            int col = cbase + in * 16 + cl;
            float bv2 = bias[col];
#pragma unroll
            for (int r = 0; r < 4; ++r) {
                size_t row = rbase + im * 16 + rl * 4 + r;
                C[row * ND + col] = acc[im][in][r] + bv2;
            }
        }
    }
}

extern "C" void kernel_launch(void* const* d_in, const int* in_sizes, int n_in,
                              void* d_out, int out_size, void* d_ws, size_t ws_size,
                              hipStream_t stream) {
    const float* x  = (const float*)d_in[0];
    const float* c0 = (const float*)d_in[1];
    const float* c1 = (const float*)d_in[2];
    const float* c2 = (const float*)d_in[3];
    const float* c3 = (const float*)d_in[4];
    const float* bias = (const float*)d_in[5];
    float* out = (float*)d_out;

    char* ws = (char*)d_ws;
    bf16_t* Xb = (bf16_t*)ws;                 // 16 MiB, fragged A
    bf16_t* W  = (bf16_t*)(ws + (16u << 20)); // 32 MiB, fragged B

    cvt_x_frag<<<4096, 256, 0, stream>>>(x, Xb);
    build_w<<<256, 256, 0, stream>>>(c0, c1, c2, c3, W);
    dim3 grid(ND / 128, BATCH_N / 128);
    gemm_frag<<<grid, 256, 0, stream>>>(Xb, W, bias, out);
}

// Round 6
// 208.605 us; speedup vs baseline: 1.4750x; 1.0178x over previous
//
#include <hip/hip_runtime.h>
#include <hip/hip_bf16.h>
#include <stdint.h>

// TT linear 4096->4096, B=2048, ranks (1,16,16,16,1), modes 8^4.
// R6: fragment-direct zero-LDS GEMM, with (a) wave-uniform base addressing
// so loads go SGPR-base + shared lane voffset (SALU offset math), and
// (b) depth-4 kc prefetch (~230 cyc load->use distance > L2 latency).
// Fragment (g, kc): rows g*16..+15, k kc*32..+31; element (row,k) at
// frag_base + lane*8 + (k&7), lane = (row&15) | (((k>>3)&3)<<4).

typedef __bf16 bf16_t;
typedef __bf16 bf16x8 __attribute__((ext_vector_type(8)));
typedef float floatx4 __attribute__((ext_vector_type(4)));

#define BATCH_N 2048
#define KD 4096
#define ND 4096

// ---- x fp32 -> bf16 fragment layout -----------------------------------
__global__ __launch_bounds__(256) void cvt_x_frag(const float* __restrict__ x,
                                                  bf16_t* __restrict__ Af) {
    const int t = threadIdx.x;
    const int fid = blockIdx.x * 4 + (t >> 6);    // 16384 frags (128 mg x 128 kc)
    const int lane = t & 63;
    const int mg = fid >> 7, kc = fid & 127;
    const int row = mg * 16 + (lane & 15);
    const int k = kc * 32 + (lane >> 4) * 8;
    const float4* xp = (const float4*)(x + (size_t)row * KD + k);
    float4 a = xp[0], b = xp[1];
    bf16x8 o;
    o[0] = (bf16_t)a.x; o[1] = (bf16_t)a.y; o[2] = (bf16_t)a.z; o[3] = (bf16_t)a.w;
    o[4] = (bf16_t)b.x; o[5] = (bf16_t)b.y; o[6] = (bf16_t)b.z; o[7] = (bf16_t)b.w;
    ((bf16x8*)(Af + (size_t)fid * 512))[lane] = o;
}

// ---- W build, straight into fragment layout ---------------------------
// Block b: M23b = b>>6 (16 consecutive j low-bits), N01 = b&63.
// j = m01*64 + M23b*16 + m23l, i = N01*64 + n23.
__global__ __launch_bounds__(256) void build_w(const float* __restrict__ c0,
                                               const float* __restrict__ c1,
                                               const float* __restrict__ c2,
                                               const float* __restrict__ c3,
                                               bf16_t* __restrict__ Bf) {
    __shared__ float c0s[128];          // [m0*16+r1], n0 fixed
    __shared__ float c1s[2048];         // [r1*128+m1*16+r2], n1 fixed
    __shared__ float c2s[2 * 2048];     // [m2l][r2*128+n2*16+r3]
    __shared__ float c3s[1024];         // [r3*64+m3*8+n3] (== c3 linear)
    __shared__ float Ps[64 * 16];       // [m01*16+r2]
    __shared__ float T1s[16 * 1025];    // [m23l*1025 + r2*64 + n23]
    const int b = blockIdx.x;           // 256
    const int M23b = b >> 6, N01 = b & 63;
    const int n0 = N01 >> 3, n1 = N01 & 7;
    const int t = threadIdx.x;

    if (t < 128) c0s[t] = c0[(t >> 4) * 128 + n0 * 16 + (t & 15)];
    for (int i = t; i < 1024; i += 256) c3s[i] = c3[i];
    for (int i = t; i < 2048; i += 256) {
        int r1 = i >> 7, m1 = (i >> 4) & 7, r2 = i & 15;
        c1s[i] = c1[(r1 * 8 + m1) * 128 + n1 * 16 + r2];
    }
    for (int i = t; i < 4096; i += 256) {
        int m2l = i >> 11, j = i & 2047;
        int r2 = j >> 7, n2 = (j >> 4) & 7, r3 = j & 15;
        c2s[i] = c2[(r2 * 8 + M23b * 2 + m2l) * 128 + n2 * 16 + r3];
    }
    __syncthreads();

    for (int i = t; i < 1024; i += 256) {   // Ps[m01][r2]
        int m01 = i >> 4, r2 = i & 15, m0 = m01 >> 3, m1 = m01 & 7;
        float s = 0.f;
#pragma unroll
        for (int r1 = 0; r1 < 16; ++r1)
            s += c0s[m0 * 16 + r1] * c1s[r1 * 128 + m1 * 16 + r2];
        Ps[i] = s;
    }
    for (int i = t; i < 16384; i += 256) {  // T1s[m23l][r2][n23]
        int m23l = i >> 10, r2 = (i >> 6) & 15, n23 = i & 63;
        int m2l = m23l >> 3, m3 = m23l & 7, n2 = n23 >> 3, n3 = n23 & 7;
        float s = 0.f;
#pragma unroll
        for (int r3 = 0; r3 < 16; ++r3)
            s += c2s[m2l * 2048 + r2 * 128 + n2 * 16 + r3] * c3s[r3 * 64 + m3 * 8 + n3];
        T1s[m23l * 1025 + r2 * 64 + n23] = s;
    }
    __syncthreads();

    // outputs: thread t = (q, lhi, m23l); writes bf16x8 chunks, coalesced/wave
    const int m23l = t & 15, lhi = (t >> 4) & 3, q = t >> 6;
    const int lane = t & 63;
#pragma unroll
    for (int mi = 0; mi < 16; ++mi) {
        int m01 = q * 16 + mi;
#pragma unroll
        for (int n23h = 0; n23h < 2; ++n23h) {
            int n23b = n23h * 32 + lhi * 8;
            bf16x8 o;
#pragma unroll
            for (int n3l = 0; n3l < 8; ++n3l) {
                float s = 0.f;
#pragma unroll
                for (int r2 = 0; r2 < 16; ++r2)
                    s += Ps[m01 * 16 + r2] * T1s[m23l * 1025 + r2 * 64 + n23b + n3l];
                o[n3l] = (bf16_t)s;
            }
            size_t ng = m01 * 4 + M23b, kc = N01 * 2 + n23h;
            ((bf16x8*)(Bf + (ng * 128 + kc) * 512))[lane] = o;
        }
    }
}

// ---- BT GEMM, fragment-direct, zero LDS / zero barriers ---------------
// grid (32 bn, 16 bm) x 256 thr (4 waves 2x2); wave tile 64x64 = 4x4 frags.
// Loads: wave-uniform fragment base, indexed by [lane] only at the load,
// so the compiler can use SGPR-base + one shared voffset. Depth-4 kc
// pipeline: LD(buf,kc+4) issued ~48 MFMAs before MM(buf) consumes it.
__global__ __launch_bounds__(256, 2) void gemm_frag(const bf16_t* __restrict__ Af,
                                                    const bf16_t* __restrict__ Bf,
                                                    const float* __restrict__ bias,
                                                    float* __restrict__ C) {
    const int t = threadIdx.x;
    const int lane = t & 63, wave = t >> 6;
    const int wm = wave >> 1, wn = wave & 1;
    const int bn = blockIdx.x, bm = blockIdx.y;

    // wave-uniform fragment base pointers (lane NOT folded in)
    const bf16_t* __restrict__ Abase = Af + (size_t)(bm * 8 + wm * 4) * 65536;
    const bf16_t* __restrict__ Bbase = Bf + (size_t)(bn * 8 + wn * 4) * 65536;

    floatx4 acc[4][4];
    floatx4 zero = {0.f, 0.f, 0.f, 0.f};
#pragma unroll
    for (int i = 0; i < 4; ++i)
#pragma unroll
        for (int j = 0; j < 4; ++j) acc[i][j] = zero;

    bf16x8 av[4][4], bv[4][4];

#define LD(buf, kc)                                                            \
    {                                                                          \
        _Pragma("unroll") for (int im = 0; im < 4; ++im)                       \
            av[buf][im] =                                                      \
                ((const bf16x8*)(Abase + ((size_t)im * 128 + (kc)) * 512))[lane]; \
        _Pragma("unroll") for (int in = 0; in < 4; ++in)                       \
            bv[buf][in] =                                                      \
                ((const bf16x8*)(Bbase + ((size_t)in * 128 + (kc)) * 512))[lane]; \
    }
#define MM(buf)                                                                \
    {                                                                          \
        _Pragma("unroll") for (int im = 0; im < 4; ++im)                       \
            _Pragma("unroll") for (int in = 0; in < 4; ++in)                   \
                acc[im][in] = __builtin_amdgcn_mfma_f32_16x16x32_bf16(         \
                    av[buf][im], bv[buf][in], acc[im][in], 0, 0, 0);           \
    }

    LD(0, 0); LD(1, 1); LD(2, 2); LD(3, 3);
    for (int kc = 0; kc < 124; kc += 4) {
        MM(0); LD(0, kc + 4);
        MM(1); LD(1, kc + 5);
        MM(2); LD(2, kc + 6);
        MM(3); LD(3, kc + 7);
    }
    MM(0); MM(1); MM(2); MM(3);
#undef LD
#undef MM

    // epilogue: D[m=(lane>>4)*4+r][n=lane&15]
    const int rl = lane >> 4, cl = lane & 15;
    const size_t rbase = (size_t)bm * 128 + wm * 64;
    const int cbase = bn * 128 + wn * 64;
#pragma unroll
    for (int im = 0; im < 4; ++im) {
#pragma unroll
        for (int in = 0; in < 4; ++in) {
            int col = cbase + in * 16 + cl;
            float bv2 = bias[col];
#pragma unroll
            for (int r = 0; r < 4; ++r) {
                size_t row = rbase + im * 16 + rl * 4 + r;
                C[row * ND + col] = acc[im][in][r] + bv2;
            }
        }
    }
}

extern "C" void kernel_launch(void* const* d_in, const int* in_sizes, int n_in,
                              void* d_out, int out_size, void* d_ws, size_t ws_size,
                              hipStream_t stream) {
    const float* x  = (const float*)d_in[0];
    const float* c0 = (const float*)d_in[1];
    const float* c1 = (const float*)d_in[2];
    const float* c2 = (const float*)d_in[3];
    const float* c3 = (const float*)d_in[4];
    const float* bias = (const float*)d_in[5];
    float* out = (float*)d_out;

    char* ws = (char*)d_ws;
    bf16_t* Xb = (bf16_t*)ws;                 // 16 MiB, fragged A
    bf16_t* W  = (bf16_t*)(ws + (16u << 20)); // 32 MiB, fragged B

    cvt_x_frag<<<4096, 256, 0, stream>>>(x, Xb);
    build_w<<<256, 256, 0, stream>>>(c0, c1, c2, c3, W);
    dim3 grid(ND / 128, BATCH_N / 128);
    gemm_frag<<<grid, 256, 0, stream>>>(Xb, W, bias, out);
}